// Round 1
// baseline (498.206 us; speedup 1.0000x reference)
//
#include <hip/hip_runtime.h>

#define NG   2000
#define NPG  50
#define EPG  800
#define F0   64
#define FH   128
#define FP   512
#define NPAD 64

// ---------------- Kernel 1: per-graph fused 3x GCNConv + mean pooling ----------------
// One block = one graph. Everything stays in LDS.
__global__ __launch_bounds__(256, 2) void gcn_fused(
    const float* __restrict__ nf,        // [N, 64] node features
    const int*   __restrict__ pair,      // [2, E]
    const int*   __restrict__ num_nodes, // [G]
    const float* __restrict__ W0, const float* __restrict__ b0,
    const float* __restrict__ W1, const float* __restrict__ b1,
    const float* __restrict__ W2, const float* __restrict__ b2,
    float* __restrict__ means)           // [G, 128] workspace out
{
    __shared__ float Xs[NPAD][FH];      // current (pre-scaled) features / agg output
    __shared__ float Hs[NPAD][FH];      // GEMM output h = (x*norm_out) @ W
    __shared__ float Wt[16][FH];        // staged W k-tile
    __shared__ unsigned short epk[EPG]; // src | dst<<8 (local ids < 50)
    __shared__ unsigned char  ssrc[EPG];// src ids sorted by dst (deterministic)
    __shared__ int   degi[NPG], dego[NPG], off[NPG + 1];
    __shared__ float nin[NPG], nout[NPG];
    __shared__ float pool[2][FH];

    const int tid   = threadIdx.x;
    const int g     = blockIdx.x;
    const int base  = g * NPG;
    const int ebase = g * EPG;
    const int* srcp = pair;             // pair[0]
    const int* dstp = pair + (size_t)NG * EPG; // pair[1]

    if (tid < NPG) { degi[tid] = 0; dego[tid] = 0; }
    __syncthreads();

    // ---- edges + degrees ----
    for (int e = tid; e < EPG; e += 256) {
        int s = srcp[ebase + e] - base;
        int d = dstp[ebase + e] - base;
        epk[e] = (unsigned short)(s | (d << 8));
        atomicAdd(&dego[s], 1);
        atomicAdd(&degi[d], 1);
    }
    __syncthreads();

    if (tid < NPG) {
        nout[tid] = rsqrtf((float)max(dego[tid], 1));
        nin[tid]  = rsqrtf((float)max(degi[tid], 1));
    }
    if (tid == 0) {
        int r = 0;
        for (int i = 0; i < NPG; ++i) { off[i] = r; r += degi[i]; }
        off[NPG] = r;
    }
    __syncthreads();

    // ---- deterministic counting sort by dst (50 lanes scan, broadcast reads) ----
    if (tid < NPG) {
        int pos = off[tid];
        for (int e = 0; e < EPG; ++e) {
            unsigned short pk = epk[e];
            if ((pk >> 8) == tid) ssrc[pos++] = (unsigned char)(pk & 0xFF);
        }
    }

    // ---- load X0, pre-scaled by norm_out; pad rows 50..63 = 0 ----
    for (int i4 = tid; i4 < NPAD * (F0 / 4); i4 += 256) {
        int n = i4 >> 4, k4 = i4 & 15;
        float4 v = make_float4(0.f, 0.f, 0.f, 0.f);
        if (n < NPG) {
            v = *(const float4*)(nf + (size_t)(base + n) * F0 + k4 * 4);
            float s = nout[n];
            v.x *= s; v.y *= s; v.z *= s; v.w *= s;
        }
        *(float4*)(&Xs[n][k4 * 4]) = v;
    }
    __syncthreads();

    const int nt = tid >> 4;   // node tile 0..15  (4 nodes each)
    const int ft = tid & 15;   // feat tile 0..15  (feats ft*4..+3 and 64+ft*4..+3)

    // Hs[0:64, 0:128] = Xs[0:64, 0:K] @ W[K,128]; W staged in 16-row tiles.
    auto gemm = [&](const float* __restrict__ W, int K) {
        float acc[4][8];
#pragma unroll
        for (int i = 0; i < 4; ++i)
#pragma unroll
            for (int c = 0; c < 8; ++c) acc[i][c] = 0.f;
        for (int kt = 0; kt < K; kt += 16) {
            __syncthreads();
            for (int i = tid; i < 16 * (FH / 4); i += 256) {
                int r = i >> 5, c4 = i & 31;
                *(float4*)(&Wt[r][c4 * 4]) =
                    *(const float4*)(W + (size_t)(kt + r) * FH + c4 * 4);
            }
            __syncthreads();
#pragma unroll
            for (int kk4 = 0; kk4 < 4; ++kk4) {
                float4 a[4];
#pragma unroll
                for (int i = 0; i < 4; ++i)
                    a[i] = *(const float4*)(&Xs[nt * 4 + i][kt + kk4 * 4]);
#pragma unroll
                for (int j = 0; j < 4; ++j) {
                    float4 w0 = *(const float4*)(&Wt[kk4 * 4 + j][ft * 4]);
                    float4 w1 = *(const float4*)(&Wt[kk4 * 4 + j][64 + ft * 4]);
#pragma unroll
                    for (int i = 0; i < 4; ++i) {
                        float ax = (j == 0) ? a[i].x : (j == 1) ? a[i].y
                                 : (j == 2) ? a[i].z : a[i].w;
                        acc[i][0] += ax * w0.x; acc[i][1] += ax * w0.y;
                        acc[i][2] += ax * w0.z; acc[i][3] += ax * w0.w;
                        acc[i][4] += ax * w1.x; acc[i][5] += ax * w1.y;
                        acc[i][6] += ax * w1.z; acc[i][7] += ax * w1.w;
                    }
                }
            }
        }
#pragma unroll
        for (int i = 0; i < 4; ++i) {
            *(float4*)(&Hs[nt * 4 + i][ft * 4]) =
                make_float4(acc[i][0], acc[i][1], acc[i][2], acc[i][3]);
            *(float4*)(&Hs[nt * 4 + i][64 + ft * 4]) =
                make_float4(acc[i][4], acc[i][5], acc[i][6], acc[i][7]);
        }
        __syncthreads();
    };

    // Xs[d,:] = relu( (sum_{e: dst=d} Hs[src_e,:]) * nin[d] + b ) [* nout[d]]
    auto aggregate = [&](const float* __restrict__ b, bool scale_out) {
        for (int it = tid; it < NPAD * (FH / 4); it += 256) {
            int d = it >> 5, f4 = it & 31;
            float4 acc = make_float4(0.f, 0.f, 0.f, 0.f);
            if (d < NPG) {
                int pe = off[d + 1];
                for (int p = off[d]; p < pe; ++p) {
                    int s = ssrc[p];
                    float4 h = *(const float4*)(&Hs[s][f4 * 4]);
                    acc.x += h.x; acc.y += h.y; acc.z += h.z; acc.w += h.w;
                }
                float4 bb = *(const float4*)(b + f4 * 4);
                float ni = nin[d];
                acc.x = fmaxf(acc.x * ni + bb.x, 0.f);
                acc.y = fmaxf(acc.y * ni + bb.y, 0.f);
                acc.z = fmaxf(acc.z * ni + bb.z, 0.f);
                acc.w = fmaxf(acc.w * ni + bb.w, 0.f);
                if (scale_out) {
                    float s = nout[d];
                    acc.x *= s; acc.y *= s; acc.z *= s; acc.w *= s;
                }
            }
            *(float4*)(&Xs[d][f4 * 4]) = acc;
        }
        __syncthreads();
    };

    gemm(W0, F0);  aggregate(b0, true);
    gemm(W1, FH);  aggregate(b1, true);
    gemm(W2, FH);  aggregate(b2, false);

    // ---- mean pooling over the graph's 50 nodes ----
    {
        int f = tid & 127, h = tid >> 7;
        float s = 0.f;
        for (int n = h * 25; n < h * 25 + 25; ++n) s += Xs[n][f];
        pool[h][f] = s;
        __syncthreads();
        if (tid < FH) {
            float m = (pool[0][tid] + pool[1][tid]) / (float)num_nodes[g];
            means[(size_t)g * FH + tid] = m;
        }
    }
}

// ---------------- Kernel 2: MLP head  out = relu(mean@Wp1+bp1)@Wp2+bp2 ----------------
__global__ __launch_bounds__(512) void mlp_head(
    const float* __restrict__ means, const float* __restrict__ Wp1,
    const float* __restrict__ bp1,   const float* __restrict__ Wp2,
    const float* __restrict__ bp2,   float* __restrict__ out)
{
    __shared__ float ms[8][FH];
    __shared__ float wred[8][8];   // [wave][graph]
    const int tid = threadIdx.x;
    const int g0  = blockIdx.x * 8;

    for (int i = tid; i < 8 * FH; i += 512)
        ms[i >> 7][i & 127] = means[(size_t)g0 * FH + i];
    __syncthreads();

    const int f = tid;             // 512 threads = 512 hidden units
    float acc[8];
    float bb = bp1[f];
#pragma unroll
    for (int gi = 0; gi < 8; ++gi) acc[gi] = bb;
    for (int k = 0; k < FH; ++k) {
        float w = Wp1[(size_t)k * FP + f];
#pragma unroll
        for (int gi = 0; gi < 8; ++gi) acc[gi] += ms[gi][k] * w;
    }
    float w2 = Wp2[f];
#pragma unroll
    for (int gi = 0; gi < 8; ++gi) {
        float v = fmaxf(acc[gi], 0.f) * w2;
#pragma unroll
        for (int o = 32; o > 0; o >>= 1) v += __shfl_down(v, o, 64);
        if ((tid & 63) == 0) wred[tid >> 6][gi] = v;
    }
    __syncthreads();
    if (tid < 8) {
        float s = 0.f;
#pragma unroll
        for (int w = 0; w < 8; ++w) s += wred[w][tid];
        out[g0 + tid] = s + bp2[0];
    }
}

extern "C" void kernel_launch(void* const* d_in, const int* in_sizes, int n_in,
                              void* d_out, int out_size, void* d_ws, size_t ws_size,
                              hipStream_t stream) {
    const float* nf   = (const float*)d_in[0];
    // d_in[1] = edge_features (unused by the model)
    const int*   pair = (const int*)d_in[2];
    const int*   nn   = (const int*)d_in[3];
    // d_in[4] = num_edges (unused)
    const float* W0  = (const float*)d_in[5];  const float* b0  = (const float*)d_in[6];
    const float* W1  = (const float*)d_in[7];  const float* b1  = (const float*)d_in[8];
    const float* W2  = (const float*)d_in[9];  const float* b2  = (const float*)d_in[10];
    const float* Wp1 = (const float*)d_in[11]; const float* bp1 = (const float*)d_in[12];
    const float* Wp2 = (const float*)d_in[13]; const float* bp2 = (const float*)d_in[14];

    float* means = (float*)d_ws;   // 2000*128*4 = 1 MB
    float* out   = (float*)d_out;  // 2000 floats

    hipLaunchKernelGGL(gcn_fused, dim3(NG), dim3(256), 0, stream,
                       nf, pair, nn, W0, b0, W1, b1, W2, b2, means);
    hipLaunchKernelGGL(mlp_head, dim3(NG / 8), dim3(512), 0, stream,
                       means, Wp1, bp1, Wp2, bp2, out);
}

// Round 2
// 271.519 us; speedup vs baseline: 1.8349x; 1.8349x over previous
//
#include <hip/hip_runtime.h>

#define NG   2000
#define NPG  50
#define EPG  800
#define F0   64
#define FH   128
#define FP   512
#define NPAD 64

__device__ inline void fma4(float4& c, float a, const float4& w) {
    c.x = fmaf(a, w.x, c.x);
    c.y = fmaf(a, w.y, c.y);
    c.z = fmaf(a, w.z, c.z);
    c.w = fmaf(a, w.w, c.w);
}
__device__ inline void add4(float4& c, const float4& h) {
    c.x += h.x; c.y += h.y; c.z += h.z; c.w += h.w;
}

// GEMM: Hs[0:64,0:128] = Xs[0:64,0:K] @ W[K,128].
// Thread tile: 8 nodes x 4 feats. A-reads are 2-way broadcast LDS; W from global (L2).
template<int K>
__device__ inline void gemm_body(const float (*__restrict__ Xs)[FH],
                                 float (*__restrict__ Hs)[FH],
                                 const float* __restrict__ W, int nt, int fc) {
    float4 acc[8];
#pragma unroll
    for (int i = 0; i < 8; ++i) acc[i] = make_float4(0.f, 0.f, 0.f, 0.f);
    const float* Wp = W + fc * 4;
#pragma unroll 2
    for (int kt = 0; kt < K; kt += 16) {
#pragma unroll
        for (int kk = 0; kk < 4; ++kk) {
            const int k0 = kt + kk * 4;
            float4 w[4];
#pragma unroll
            for (int j = 0; j < 4; ++j)
                w[j] = *(const float4*)(Wp + (size_t)(k0 + j) * FH);
            float4 a[8];
#pragma unroll
            for (int i = 0; i < 8; ++i)
                a[i] = *(const float4*)(&Xs[nt * 8 + i][k0]);
#pragma unroll
            for (int i = 0; i < 8; ++i) {
                fma4(acc[i], a[i].x, w[0]);
                fma4(acc[i], a[i].y, w[1]);
                fma4(acc[i], a[i].z, w[2]);
                fma4(acc[i], a[i].w, w[3]);
            }
        }
    }
#pragma unroll
    for (int i = 0; i < 8; ++i)
        *(float4*)(&Hs[nt * 8 + i][fc * 4]) = acc[i];
}

__global__ __launch_bounds__(256, 2) void gcn_fused(
    const float* __restrict__ nf,
    const int*   __restrict__ pair,
    const int*   __restrict__ num_nodes,
    const float* __restrict__ W0, const float* __restrict__ b0,
    const float* __restrict__ W1, const float* __restrict__ b1,
    const float* __restrict__ W2, const float* __restrict__ b2,
    float* __restrict__ means)
{
    __shared__ float Xs[NPAD][FH];
    __shared__ float Hs[NPAD][FH];
    __shared__ unsigned char ssrc[EPG];
    __shared__ int   degi[NPG], dego[NPG], off[NPG], cur[NPG];
    __shared__ float nin[NPG], nout[NPG];
    __shared__ float pool[2][FH];

    const int tid   = threadIdx.x;
    const int g     = blockIdx.x;
    const int base  = g * NPG;
    const int ebase = g * EPG;
    const int* srcp = pair;
    const int* dstp = pair + (size_t)NG * EPG;

    if (tid < NPG) { degi[tid] = 0; dego[tid] = 0; cur[tid] = 0; }
    __syncthreads();

    // ---- degrees ----
    for (int e = tid; e < EPG; e += 256) {
        int s = srcp[ebase + e] - base;
        int d = dstp[ebase + e] - base;
        atomicAdd(&dego[s], 1);
        atomicAdd(&degi[d], 1);
    }
    __syncthreads();

    // ---- norms + exclusive prefix scan of in-degrees (wave 0) ----
    if (tid < NPG) {
        nout[tid] = rsqrtf((float)max(dego[tid], 1));
        nin[tid]  = rsqrtf((float)max(degi[tid], 1));
    }
    if (tid < 64) {
        int v = (tid < NPG) ? degi[tid] : 0;
        int s = v;
#pragma unroll
        for (int o = 1; o < 64; o <<= 1) {
            int t = __shfl_up(s, o, 64);
            if (tid >= o) s += t;
        }
        if (tid < NPG) off[tid] = s - v;
    }
    __syncthreads();

    // ---- parallel bucket placement (order within bucket is arbitrary) ----
    for (int e = tid; e < EPG; e += 256) {
        int s = srcp[ebase + e] - base;
        int d = dstp[ebase + e] - base;
        int p = atomicAdd(&cur[d], 1);
        ssrc[off[d] + p] = (unsigned char)s;
    }
    // ---- load X0 scaled by norm_out; pad rows zero ----
    for (int i4 = tid; i4 < NPAD * (F0 / 4); i4 += 256) {
        int n = i4 >> 4, k4 = i4 & 15;
        float4 v = make_float4(0.f, 0.f, 0.f, 0.f);
        if (n < NPG) {
            v = *(const float4*)(nf + (size_t)(base + n) * F0 + k4 * 4);
            float sc = nout[n];
            v.x *= sc; v.y *= sc; v.z *= sc; v.w *= sc;
        }
        *(float4*)(&Xs[n][k4 * 4]) = v;
    }
    __syncthreads();

    const int nt = tid >> 5;   // 0..7  : nodes nt*8..nt*8+7
    const int fc = tid & 31;   // 0..31 : feats fc*4..fc*4+3

    // Xs[d,:] = relu(agg * nin + b) [* nout], pad rows zeroed. (d, f8) items, 2-way ILP.
    auto aggregate = [&](const float* __restrict__ b, bool scale_out) {
        for (int it = tid; it < NPAD * 16; it += 256) {
            int d = it >> 4, f8 = (it & 15) * 8;
            float4 s0a = make_float4(0.f, 0.f, 0.f, 0.f), s1a = s0a;
            float4 s0b = s0a, s1b = s0a;
            float4 r0 = s0a, r1 = s0a;
            if (d < NPG) {
                int p0 = off[d], cnt = degi[d];
                int p = 0;
                for (; p + 2 <= cnt; p += 2) {
                    int sA = ssrc[p0 + p], sB = ssrc[p0 + p + 1];
                    add4(s0a, *(const float4*)(&Hs[sA][f8]));
                    add4(s1a, *(const float4*)(&Hs[sA][f8 + 4]));
                    add4(s0b, *(const float4*)(&Hs[sB][f8]));
                    add4(s1b, *(const float4*)(&Hs[sB][f8 + 4]));
                }
                if (p < cnt) {
                    int sA = ssrc[p0 + p];
                    add4(s0a, *(const float4*)(&Hs[sA][f8]));
                    add4(s1a, *(const float4*)(&Hs[sA][f8 + 4]));
                }
                add4(s0a, s0b); add4(s1a, s1b);
                float ni = nin[d];
                float4 bb0 = *(const float4*)(b + f8);
                float4 bb1 = *(const float4*)(b + f8 + 4);
                r0.x = fmaxf(fmaf(s0a.x, ni, bb0.x), 0.f);
                r0.y = fmaxf(fmaf(s0a.y, ni, bb0.y), 0.f);
                r0.z = fmaxf(fmaf(s0a.z, ni, bb0.z), 0.f);
                r0.w = fmaxf(fmaf(s0a.w, ni, bb0.w), 0.f);
                r1.x = fmaxf(fmaf(s1a.x, ni, bb1.x), 0.f);
                r1.y = fmaxf(fmaf(s1a.y, ni, bb1.y), 0.f);
                r1.z = fmaxf(fmaf(s1a.z, ni, bb1.z), 0.f);
                r1.w = fmaxf(fmaf(s1a.w, ni, bb1.w), 0.f);
                if (scale_out) {
                    float sc = nout[d];
                    r0.x *= sc; r0.y *= sc; r0.z *= sc; r0.w *= sc;
                    r1.x *= sc; r1.y *= sc; r1.z *= sc; r1.w *= sc;
                }
            }
            *(float4*)(&Xs[d][f8])     = r0;
            *(float4*)(&Xs[d][f8 + 4]) = r1;
        }
        __syncthreads();
    };

    gemm_body<F0>(Xs, Hs, W0, nt, fc);  __syncthreads();  aggregate(b0, true);
    gemm_body<FH>(Xs, Hs, W1, nt, fc);  __syncthreads();  aggregate(b1, true);
    gemm_body<FH>(Xs, Hs, W2, nt, fc);  __syncthreads();  aggregate(b2, false);

    // ---- mean pooling ----
    {
        int f = tid & 127, h = tid >> 7;
        float s = 0.f;
        for (int n = h * 25; n < h * 25 + 25; ++n) s += Xs[n][f];
        pool[h][f] = s;
        __syncthreads();
        if (tid < FH) {
            float m = (pool[0][tid] + pool[1][tid]) / (float)num_nodes[g];
            means[(size_t)g * FH + tid] = m;
        }
    }
}

// ---------------- Kernel 2: MLP head ----------------
__global__ __launch_bounds__(512) void mlp_head(
    const float* __restrict__ means, const float* __restrict__ Wp1,
    const float* __restrict__ bp1,   const float* __restrict__ Wp2,
    const float* __restrict__ bp2,   float* __restrict__ out)
{
    __shared__ float ms[8][FH];
    __shared__ float wred[8][8];
    const int tid = threadIdx.x;
    const int g0  = blockIdx.x * 8;

    for (int i = tid; i < 8 * FH; i += 512)
        ms[i >> 7][i & 127] = means[(size_t)g0 * FH + i];
    __syncthreads();

    const int f = tid;
    float acc[8];
    float bb = bp1[f];
#pragma unroll
    for (int gi = 0; gi < 8; ++gi) acc[gi] = bb;
    for (int k = 0; k < FH; ++k) {
        float w = Wp1[(size_t)k * FP + f];
#pragma unroll
        for (int gi = 0; gi < 8; ++gi) acc[gi] += ms[gi][k] * w;
    }
    float w2 = Wp2[f];
#pragma unroll
    for (int gi = 0; gi < 8; ++gi) {
        float v = fmaxf(acc[gi], 0.f) * w2;
#pragma unroll
        for (int o = 32; o > 0; o >>= 1) v += __shfl_down(v, o, 64);
        if ((tid & 63) == 0) wred[tid >> 6][gi] = v;
    }
    __syncthreads();
    if (tid < 8) {
        float s = 0.f;
#pragma unroll
        for (int w = 0; w < 8; ++w) s += wred[w][tid];
        out[g0 + tid] = s + bp2[0];
    }
}

extern "C" void kernel_launch(void* const* d_in, const int* in_sizes, int n_in,
                              void* d_out, int out_size, void* d_ws, size_t ws_size,
                              hipStream_t stream) {
    const float* nf   = (const float*)d_in[0];
    const int*   pair = (const int*)d_in[2];
    const int*   nn   = (const int*)d_in[3];
    const float* W0  = (const float*)d_in[5];  const float* b0  = (const float*)d_in[6];
    const float* W1  = (const float*)d_in[7];  const float* b1  = (const float*)d_in[8];
    const float* W2  = (const float*)d_in[9];  const float* b2  = (const float*)d_in[10];
    const float* Wp1 = (const float*)d_in[11]; const float* bp1 = (const float*)d_in[12];
    const float* Wp2 = (const float*)d_in[13]; const float* bp2 = (const float*)d_in[14];

    float* means = (float*)d_ws;   // 2000*128*4 = 1 MB
    float* out   = (float*)d_out;

    hipLaunchKernelGGL(gcn_fused, dim3(NG), dim3(256), 0, stream,
                       nf, pair, nn, W0, b0, W1, b1, W2, b2, means);
    hipLaunchKernelGGL(mlp_head, dim3(NG / 8), dim3(512), 0, stream,
                       means, Wp1, bp1, Wp2, bp2, out);
}

// Round 3
// 210.198 us; speedup vs baseline: 2.3702x; 1.2917x over previous
//
#include <hip/hip_runtime.h>

#define NG   2000
#define NPG  50
#define EPG  800
#define F0   64
#define FH   128
#define FHP  132   // padded row stride (rotates bank origin by 4 per row)
#define FP   512
#define NPAD 64

__device__ inline void fma4(float4& c, float a, const float4& w) {
    c.x = fmaf(a, w.x, c.x);
    c.y = fmaf(a, w.y, c.y);
    c.z = fmaf(a, w.z, c.z);
    c.w = fmaf(a, w.w, c.w);
}
__device__ inline void add4(float4& c, const float4& h) {
    c.x += h.x; c.y += h.y; c.z += h.z; c.w += h.w;
}

// GEMM: Hs[0:64,0:128] = Xs[0:64,0:K] @ W[K,128].
// 512 threads: nt=tid>>5 (16 groups x 4 nodes), fc=tid&31 (32 x 4 feats).
// A-reads: 32-lane same-address broadcast from LDS. W: coalesced 512B/wave from L2.
template<int K>
__device__ inline void gemm_body(const float (*__restrict__ Xs)[FHP],
                                 float (*__restrict__ Hs)[FHP],
                                 const float* __restrict__ W, int nt, int fc) {
    float4 acc[4];
#pragma unroll
    for (int i = 0; i < 4; ++i) acc[i] = make_float4(0.f, 0.f, 0.f, 0.f);
    const float* Wp = W + fc * 4;
#pragma unroll 4
    for (int k0 = 0; k0 < K; k0 += 4) {
        float4 w[4];
#pragma unroll
        for (int j = 0; j < 4; ++j)
            w[j] = *(const float4*)(Wp + (size_t)(k0 + j) * FH);
        float4 a[4];
#pragma unroll
        for (int i = 0; i < 4; ++i)
            a[i] = *(const float4*)(&Xs[nt * 4 + i][k0]);
#pragma unroll
        for (int i = 0; i < 4; ++i) {
            fma4(acc[i], a[i].x, w[0]);
            fma4(acc[i], a[i].y, w[1]);
            fma4(acc[i], a[i].z, w[2]);
            fma4(acc[i], a[i].w, w[3]);
        }
    }
#pragma unroll
    for (int i = 0; i < 4; ++i)
        *(float4*)(&Hs[nt * 4 + i][fc * 4]) = acc[i];
}

__global__ __launch_bounds__(512, 2) void gcn_fused(
    const float* __restrict__ nf,
    const int*   __restrict__ pair,
    const int*   __restrict__ num_nodes,
    const float* __restrict__ W0, const float* __restrict__ b0,
    const float* __restrict__ W1, const float* __restrict__ b1,
    const float* __restrict__ W2, const float* __restrict__ b2,
    float* __restrict__ means)
{
    __shared__ float Xs[NPAD][FHP];
    __shared__ float Hs[NPAD][FHP];
    __shared__ unsigned char ssrc[EPG];
    __shared__ int   degi[NPG], dego[NPG], off[NPG], cur[NPG];
    __shared__ float nin[NPG], nout[NPG];
    __shared__ float pool[4][FH];

    const int tid   = threadIdx.x;
    const int g     = blockIdx.x;
    const int base  = g * NPG;
    const int ebase = g * EPG;
    const int* srcp = pair;
    const int* dstp = pair + (size_t)NG * EPG;

    if (tid < NPG) { degi[tid] = 0; dego[tid] = 0; cur[tid] = 0; }
    __syncthreads();

    // ---- degrees ----
    for (int e = tid; e < EPG; e += 512) {
        int s = srcp[ebase + e] - base;
        int d = dstp[ebase + e] - base;
        atomicAdd(&dego[s], 1);
        atomicAdd(&degi[d], 1);
    }
    __syncthreads();

    // ---- norms + exclusive prefix scan of in-degrees (wave 0) ----
    if (tid < NPG) {
        nout[tid] = rsqrtf((float)max(dego[tid], 1));
        nin[tid]  = rsqrtf((float)max(degi[tid], 1));
    }
    if (tid < 64) {
        int v = (tid < NPG) ? degi[tid] : 0;
        int s = v;
#pragma unroll
        for (int o = 1; o < 64; o <<= 1) {
            int t = __shfl_up(s, o, 64);
            if (tid >= o) s += t;
        }
        if (tid < NPG) off[tid] = s - v;
    }
    __syncthreads();

    // ---- parallel bucket placement (order within bucket arbitrary; sum is fp-commutative enough) ----
    for (int e = tid; e < EPG; e += 512) {
        int s = srcp[ebase + e] - base;
        int d = dstp[ebase + e] - base;
        int p = atomicAdd(&cur[d], 1);
        ssrc[off[d] + p] = (unsigned char)s;
    }
    // ---- load X0 scaled by norm_out; pad rows zero ----
    for (int i4 = tid; i4 < NPAD * (F0 / 4); i4 += 512) {
        int n = i4 >> 4, k4 = i4 & 15;
        float4 v = make_float4(0.f, 0.f, 0.f, 0.f);
        if (n < NPG) {
            v = *(const float4*)(nf + (size_t)(base + n) * F0 + k4 * 4);
            float sc = nout[n];
            v.x *= sc; v.y *= sc; v.z *= sc; v.w *= sc;
        }
        *(float4*)(&Xs[n][k4 * 4]) = v;
    }
    __syncthreads();

    const int nt = tid >> 5;   // 0..15 : nodes nt*4..nt*4+3
    const int fc = tid & 31;   // 0..31 : feats fc*4..fc*4+3

    // Xs[d,:] = relu(agg * nin + b) [* nout], pad rows zeroed. (d, f8) items, 2-way ILP.
    auto aggregate = [&](const float* __restrict__ b, bool scale_out) {
#pragma unroll
        for (int it = tid; it < NPAD * 16; it += 512) {
            int d = it >> 4, f8 = (it & 15) * 8;
            float4 s0a = make_float4(0.f, 0.f, 0.f, 0.f), s1a = s0a;
            float4 s0b = s0a, s1b = s0a;
            float4 r0 = s0a, r1 = s0a;
            if (d < NPG) {
                int p0 = off[d], cnt = degi[d];
                int p = 0;
                for (; p + 2 <= cnt; p += 2) {
                    int sA = ssrc[p0 + p], sB = ssrc[p0 + p + 1];
                    add4(s0a, *(const float4*)(&Hs[sA][f8]));
                    add4(s1a, *(const float4*)(&Hs[sA][f8 + 4]));
                    add4(s0b, *(const float4*)(&Hs[sB][f8]));
                    add4(s1b, *(const float4*)(&Hs[sB][f8 + 4]));
                }
                if (p < cnt) {
                    int sA = ssrc[p0 + p];
                    add4(s0a, *(const float4*)(&Hs[sA][f8]));
                    add4(s1a, *(const float4*)(&Hs[sA][f8 + 4]));
                }
                add4(s0a, s0b); add4(s1a, s1b);
                float ni = nin[d];
                float4 bb0 = *(const float4*)(b + f8);
                float4 bb1 = *(const float4*)(b + f8 + 4);
                r0.x = fmaxf(fmaf(s0a.x, ni, bb0.x), 0.f);
                r0.y = fmaxf(fmaf(s0a.y, ni, bb0.y), 0.f);
                r0.z = fmaxf(fmaf(s0a.z, ni, bb0.z), 0.f);
                r0.w = fmaxf(fmaf(s0a.w, ni, bb0.w), 0.f);
                r1.x = fmaxf(fmaf(s1a.x, ni, bb1.x), 0.f);
                r1.y = fmaxf(fmaf(s1a.y, ni, bb1.y), 0.f);
                r1.z = fmaxf(fmaf(s1a.z, ni, bb1.z), 0.f);
                r1.w = fmaxf(fmaf(s1a.w, ni, bb1.w), 0.f);
                if (scale_out) {
                    float sc = nout[d];
                    r0.x *= sc; r0.y *= sc; r0.z *= sc; r0.w *= sc;
                    r1.x *= sc; r1.y *= sc; r1.z *= sc; r1.w *= sc;
                }
            }
            *(float4*)(&Xs[d][f8])     = r0;
            *(float4*)(&Xs[d][f8 + 4]) = r1;
        }
        __syncthreads();
    };

    gemm_body<F0>(Xs, Hs, W0, nt, fc);  __syncthreads();  aggregate(b0, true);
    gemm_body<FH>(Xs, Hs, W1, nt, fc);  __syncthreads();  aggregate(b1, true);
    gemm_body<FH>(Xs, Hs, W2, nt, fc);  __syncthreads();  aggregate(b2, false);

    // ---- mean pooling: 4 groups of 128 threads, stride-4 node sums ----
    {
        int f = tid & 127, h = tid >> 7;
        float s = 0.f;
        for (int n = h; n < NPG; n += 4) s += Xs[n][f];
        pool[h][f] = s;
        __syncthreads();
        if (tid < FH) {
            float m = (pool[0][tid] + pool[1][tid] + pool[2][tid] + pool[3][tid])
                      / (float)num_nodes[g];
            means[(size_t)g * FH + tid] = m;
        }
    }
}

// ---------------- Kernel 2: MLP head ----------------
__global__ __launch_bounds__(512) void mlp_head(
    const float* __restrict__ means, const float* __restrict__ Wp1,
    const float* __restrict__ bp1,   const float* __restrict__ Wp2,
    const float* __restrict__ bp2,   float* __restrict__ out)
{
    __shared__ float ms[8][FH];
    __shared__ float wred[8][8];
    const int tid = threadIdx.x;
    const int g0  = blockIdx.x * 8;

    for (int i = tid; i < 8 * FH; i += 512)
        ms[i >> 7][i & 127] = means[(size_t)g0 * FH + i];
    __syncthreads();

    const int f = tid;
    float acc[8];
    float bb = bp1[f];
#pragma unroll
    for (int gi = 0; gi < 8; ++gi) acc[gi] = bb;
    for (int k = 0; k < FH; ++k) {
        float w = Wp1[(size_t)k * FP + f];
#pragma unroll
        for (int gi = 0; gi < 8; ++gi) acc[gi] += ms[gi][k] * w;
    }
    float w2 = Wp2[f];
#pragma unroll
    for (int gi = 0; gi < 8; ++gi) {
        float v = fmaxf(acc[gi], 0.f) * w2;
#pragma unroll
        for (int o = 32; o > 0; o >>= 1) v += __shfl_down(v, o, 64);
        if ((tid & 63) == 0) wred[tid >> 6][gi] = v;
    }
    __syncthreads();
    if (tid < 8) {
        float s = 0.f;
#pragma unroll
        for (int w = 0; w < 8; ++w) s += wred[w][tid];
        out[g0 + tid] = s + bp2[0];
    }
}

extern "C" void kernel_launch(void* const* d_in, const int* in_sizes, int n_in,
                              void* d_out, int out_size, void* d_ws, size_t ws_size,
                              hipStream_t stream) {
    const float* nf   = (const float*)d_in[0];
    const int*   pair = (const int*)d_in[2];
    const int*   nn   = (const int*)d_in[3];
    const float* W0  = (const float*)d_in[5];  const float* b0  = (const float*)d_in[6];
    const float* W1  = (const float*)d_in[7];  const float* b1  = (const float*)d_in[8];
    const float* W2  = (const float*)d_in[9];  const float* b2  = (const float*)d_in[10];
    const float* Wp1 = (const float*)d_in[11]; const float* bp1 = (const float*)d_in[12];
    const float* Wp2 = (const float*)d_in[13]; const float* bp2 = (const float*)d_in[14];

    float* means = (float*)d_ws;   // 2000*128*4 = 1 MB
    float* out   = (float*)d_out;

    hipLaunchKernelGGL(gcn_fused, dim3(NG), dim3(512), 0, stream,
                       nf, pair, nn, W0, b0, W1, b1, W2, b2, means);
    hipLaunchKernelGGL(mlp_head, dim3(NG / 8), dim3(512), 0, stream,
                       means, Wp1, bp1, Wp2, bp2, out);
}

// Round 4
// 194.002 us; speedup vs baseline: 2.5680x; 1.0835x over previous
//
#include <hip/hip_runtime.h>

#define NG   2000
#define NPG  50
#define EPG  800
#define F0   64
#define FH   128
#define FHP  132   // Hs row stride (float4-aligned, bank-rotating)
#define NN   65    // XsT row stride (node dim + 1 pad -> conflict-free lane reads)
#define FP   512
#define NPAD 64

__device__ inline void fma4(float4& c, float a, const float4& w) {
    c.x = fmaf(a, w.x, c.x);
    c.y = fmaf(a, w.y, c.y);
    c.z = fmaf(a, w.z, c.z);
    c.w = fmaf(a, w.w, c.w);
}
__device__ inline void add4(float4& c, const float4& h) {
    c.x += h.x; c.y += h.y; c.z += h.z; c.w += h.w;
}

// Column-split GEMM: Hs[0:64, 16w..16w+15] = XsT[0:K, lane]^T @ W[:, 16w..16w+15]
// lane = node (conflict-free b32 LDS reads); W loads are wave-uniform -> s_load.
template<int K>
__device__ inline void gemm_body(const float (*__restrict__ XsT)[NN],
                                 float (*__restrict__ Hs)[FHP],
                                 const float* __restrict__ W, int lane, int w) {
    float4 acc[4];
#pragma unroll
    for (int i = 0; i < 4; ++i) acc[i] = make_float4(0.f, 0.f, 0.f, 0.f);
    const float* Wp = W + w * 16;   // w is SGPR (readfirstlane) -> scalar loads
#pragma unroll 4
    for (int k = 0; k < K; ++k) {
        float a = XsT[k][lane];
        float4 w0 = *(const float4*)(Wp + (size_t)k * FH);
        float4 w1 = *(const float4*)(Wp + (size_t)k * FH + 4);
        float4 w2 = *(const float4*)(Wp + (size_t)k * FH + 8);
        float4 w3 = *(const float4*)(Wp + (size_t)k * FH + 12);
        fma4(acc[0], a, w0);
        fma4(acc[1], a, w1);
        fma4(acc[2], a, w2);
        fma4(acc[3], a, w3);
    }
#pragma unroll
    for (int j = 0; j < 4; ++j)
        *(float4*)(&Hs[lane][w * 16 + j * 4]) = acc[j];
}

__global__ __launch_bounds__(512, 2) void gcn_fused(
    const float* __restrict__ nf,
    const int*   __restrict__ pair,
    const int*   __restrict__ num_nodes,
    const float* __restrict__ W0, const float* __restrict__ b0,
    const float* __restrict__ W1, const float* __restrict__ b1,
    const float* __restrict__ W2, const float* __restrict__ b2,
    float* __restrict__ means)
{
    __shared__ float XsT[FH][NN];      // transposed activations [feat][node]
    __shared__ float Hs[NPAD][FHP];    // GEMM output, row-major [node][feat]
    __shared__ unsigned char ssrc[EPG];
    __shared__ int   degi[NPG], dego[NPG], off[NPG], cur[NPG];
    __shared__ float nin[NPG], nout[NPG];
    __shared__ float pool[4][FH];

    const int tid   = threadIdx.x;
    const int g     = blockIdx.x;
    const int base  = g * NPG;
    const int ebase = g * EPG;
    const int* srcp = pair;
    const int* dstp = pair + (size_t)NG * EPG;

    if (tid < NPG) { degi[tid] = 0; dego[tid] = 0; cur[tid] = 0; }
    __syncthreads();

    // ---- degrees ----
    for (int e = tid; e < EPG; e += 512) {
        int s = srcp[ebase + e] - base;
        int d = dstp[ebase + e] - base;
        atomicAdd(&dego[s], 1);
        atomicAdd(&degi[d], 1);
    }
    __syncthreads();

    // ---- norms + exclusive prefix scan of in-degrees (wave 0) ----
    if (tid < NPG) {
        nout[tid] = rsqrtf((float)max(dego[tid], 1));
        nin[tid]  = rsqrtf((float)max(degi[tid], 1));
    }
    if (tid < 64) {
        int v = (tid < NPG) ? degi[tid] : 0;
        int s = v;
#pragma unroll
        for (int o = 1; o < 64; o <<= 1) {
            int t = __shfl_up(s, o, 64);
            if (tid >= o) s += t;
        }
        if (tid < NPG) off[tid] = s - v;
    }
    __syncthreads();

    // ---- parallel bucket placement (order within bucket arbitrary) ----
    for (int e = tid; e < EPG; e += 512) {
        int s = srcp[ebase + e] - base;
        int d = dstp[ebase + e] - base;
        int p = atomicAdd(&cur[d], 1);
        ssrc[off[d] + p] = (unsigned char)s;
    }
    // ---- load X0 scaled by norm_out, store transposed; pad cols zero ----
    for (int i4 = tid; i4 < NPAD * (F0 / 4); i4 += 512) {
        int n = i4 >> 4, k4 = i4 & 15;
        float4 v = make_float4(0.f, 0.f, 0.f, 0.f);
        if (n < NPG) {
            v = *(const float4*)(nf + (size_t)(base + n) * F0 + k4 * 4);
            float sc = nout[n];
            v.x *= sc; v.y *= sc; v.z *= sc; v.w *= sc;
        }
        XsT[k4 * 4 + 0][n] = v.x;
        XsT[k4 * 4 + 1][n] = v.y;
        XsT[k4 * 4 + 2][n] = v.z;
        XsT[k4 * 4 + 3][n] = v.w;
    }
    __syncthreads();

    const int lane = tid & 63;
    const int wv   = __builtin_amdgcn_readfirstlane(tid >> 6);   // wave id -> SGPR

    // XsT[f, d] = relu(agg * nin + b) [* nout]; pads zeroed.
    auto aggregate = [&](const float* __restrict__ b, bool scale_out) {
#pragma unroll
        for (int it = tid; it < NPAD * 16; it += 512) {
            int d = it >> 4, f8 = (it & 15) * 8;
            float4 s0a = make_float4(0.f, 0.f, 0.f, 0.f), s1a = s0a;
            float4 s0b = s0a, s1b = s0a;
            float4 r0 = s0a, r1 = s0a;
            if (d < NPG) {
                int p0 = off[d], cnt = degi[d];
                int p = 0;
                for (; p + 2 <= cnt; p += 2) {
                    int sA = ssrc[p0 + p], sB = ssrc[p0 + p + 1];
                    add4(s0a, *(const float4*)(&Hs[sA][f8]));
                    add4(s1a, *(const float4*)(&Hs[sA][f8 + 4]));
                    add4(s0b, *(const float4*)(&Hs[sB][f8]));
                    add4(s1b, *(const float4*)(&Hs[sB][f8 + 4]));
                }
                if (p < cnt) {
                    int sA = ssrc[p0 + p];
                    add4(s0a, *(const float4*)(&Hs[sA][f8]));
                    add4(s1a, *(const float4*)(&Hs[sA][f8 + 4]));
                }
                add4(s0a, s0b); add4(s1a, s1b);
                float ni = nin[d];
                float4 bb0 = *(const float4*)(b + f8);
                float4 bb1 = *(const float4*)(b + f8 + 4);
                r0.x = fmaxf(fmaf(s0a.x, ni, bb0.x), 0.f);
                r0.y = fmaxf(fmaf(s0a.y, ni, bb0.y), 0.f);
                r0.z = fmaxf(fmaf(s0a.z, ni, bb0.z), 0.f);
                r0.w = fmaxf(fmaf(s0a.w, ni, bb0.w), 0.f);
                r1.x = fmaxf(fmaf(s1a.x, ni, bb1.x), 0.f);
                r1.y = fmaxf(fmaf(s1a.y, ni, bb1.y), 0.f);
                r1.z = fmaxf(fmaf(s1a.z, ni, bb1.z), 0.f);
                r1.w = fmaxf(fmaf(s1a.w, ni, bb1.w), 0.f);
                if (scale_out) {
                    float sc = nout[d];
                    r0.x *= sc; r0.y *= sc; r0.z *= sc; r0.w *= sc;
                    r1.x *= sc; r1.y *= sc; r1.z *= sc; r1.w *= sc;
                }
            }
            // scatter-write transposed for the next GEMM's A-reads
            XsT[f8 + 0][d] = r0.x;
            XsT[f8 + 1][d] = r0.y;
            XsT[f8 + 2][d] = r0.z;
            XsT[f8 + 3][d] = r0.w;
            XsT[f8 + 4][d] = r1.x;
            XsT[f8 + 5][d] = r1.y;
            XsT[f8 + 6][d] = r1.z;
            XsT[f8 + 7][d] = r1.w;
        }
        __syncthreads();
    };

    gemm_body<F0>(XsT, Hs, W0, lane, wv);  __syncthreads();  aggregate(b0, true);
    gemm_body<FH>(XsT, Hs, W1, lane, wv);  __syncthreads();  aggregate(b1, true);
    gemm_body<FH>(XsT, Hs, W2, lane, wv);  __syncthreads();  aggregate(b2, false);

    // ---- mean pooling: reads XsT rows (conflict-free) ----
    {
        int f = tid & 127, h = tid >> 7;
        float s = 0.f;
        for (int n = h; n < NPG; n += 4) s += XsT[f][n];
        pool[h][f] = s;
        __syncthreads();
        if (tid < FH) {
            float m = (pool[0][tid] + pool[1][tid] + pool[2][tid] + pool[3][tid])
                      / (float)num_nodes[g];
            means[(size_t)g * FH + tid] = m;
        }
    }
}

// ---------------- Kernel 2: MLP head ----------------
__global__ __launch_bounds__(512) void mlp_head(
    const float* __restrict__ means, const float* __restrict__ Wp1,
    const float* __restrict__ bp1,   const float* __restrict__ Wp2,
    const float* __restrict__ bp2,   float* __restrict__ out)
{
    __shared__ float ms[8][FH];
    __shared__ float wred[8][8];
    const int tid = threadIdx.x;
    const int g0  = blockIdx.x * 8;

    for (int i = tid; i < 8 * FH; i += 512)
        ms[i >> 7][i & 127] = means[(size_t)g0 * FH + i];
    __syncthreads();

    const int f = tid;
    float acc[8];
    float bb = bp1[f];
#pragma unroll
    for (int gi = 0; gi < 8; ++gi) acc[gi] = bb;
    for (int k = 0; k < FH; ++k) {
        float w = Wp1[(size_t)k * FP + f];
#pragma unroll
        for (int gi = 0; gi < 8; ++gi) acc[gi] += ms[gi][k] * w;
    }
    float w2 = Wp2[f];
#pragma unroll
    for (int gi = 0; gi < 8; ++gi) {
        float v = fmaxf(acc[gi], 0.f) * w2;
#pragma unroll
        for (int o = 32; o > 0; o >>= 1) v += __shfl_down(v, o, 64);
        if ((tid & 63) == 0) wred[tid >> 6][gi] = v;
    }
    __syncthreads();
    if (tid < 8) {
        float s = 0.f;
#pragma unroll
        for (int w = 0; w < 8; ++w) s += wred[w][tid];
        out[g0 + tid] = s + bp2[0];
    }
}

extern "C" void kernel_launch(void* const* d_in, const int* in_sizes, int n_in,
                              void* d_out, int out_size, void* d_ws, size_t ws_size,
                              hipStream_t stream) {
    const float* nf   = (const float*)d_in[0];
    const int*   pair = (const int*)d_in[2];
    const int*   nn   = (const int*)d_in[3];
    const float* W0  = (const float*)d_in[5];  const float* b0  = (const float*)d_in[6];
    const float* W1  = (const float*)d_in[7];  const float* b1  = (const float*)d_in[8];
    const float* W2  = (const float*)d_in[9];  const float* b2  = (const float*)d_in[10];
    const float* Wp1 = (const float*)d_in[11]; const float* bp1 = (const float*)d_in[12];
    const float* Wp2 = (const float*)d_in[13]; const float* bp2 = (const float*)d_in[14];

    float* means = (float*)d_ws;   // 2000*128*4 = 1 MB
    float* out   = (float*)d_out;

    hipLaunchKernelGGL(gcn_fused, dim3(NG), dim3(512), 0, stream,
                       nf, pair, nn, W0, b0, W1, b1, W2, b2, means);
    hipLaunchKernelGGL(mlp_head, dim3(NG / 8), dim3(512), 0, stream,
                       means, Wp1, bp1, Wp2, bp2, out);
}